// Round 19
// baseline (211.233 us; speedup 1.0000x reference)
//
#include <hip/hip_runtime.h>
#include <math.h>

#define N3 262144           // 64^3

// ===========================================================================
// Derived-feature formulation (verified R4-R18). R19: y's 16 scalar channels
// stored as bf16 PAIRS (uint32 = 2ch) -> conv2 scalar-tap VMEM count halves
// (80->40 instrs/thread). Vector channels stay f32 planar. ws_size=256MiB
// (observed from harness poison fill) -> extra buffers are safe.
// ===========================================================================

// Table layout (floats):
// conv1 (448): T1c[8][24]@0, T1f[8][24]@192, T1v[8][8]@384
// conv2 (1280)@448: T2c[16][24]@+0, T2f[16][24]@+384, T2sv[16][8]@+768,
//   T2vs[8][24]@+896, T2v0c[8][8]@+1088, T2v0f[8][8]@+1152, T2v1[8][8]@+1216
#define TBL_TOTAL 1728

__device__ inline void lattice_emb(int p, float* embr) {
    int i = p / 9, j = (p / 3) % 3, k = p % 3;
    float gx = (float)(i - 1), gy = (float)(j - 1), gz = (float)(k - 1);
    float r = sqrtf(gx * gx + gy * gy + gz * gz);
    const float centers[4] = {0.f, 0.33333334f, 0.6666667f, 1.f};
    const float step = 0.33333334f;
    #pragma unroll
    for (int b = 0; b < 4; b++) {
        float dd = (r - centers[b]) / step;
        float e = 0.f;
        if (fabsf(dd) < 1.f)
            e = 1.14136f * expf(2.f) * expf(-1.f / fmaxf(1.f - dd * dd, 1e-9f));
        embr[b] = e;
    }
}

// Also zeroes the BN stats buffers (threads TBL_TOTAL..TBL_TOTAL+143).
__global__ __launch_bounds__(256) void build_tables_kernel(
        const float* __restrict__ w1,  const float* __restrict__ sc1,
        const float* __restrict__ w2,  const float* __restrict__ sc2s,
        const float* __restrict__ sc2v, float* __restrict__ T,
        float* __restrict__ stats1, float* __restrict__ stats2) {
    int gid = blockIdx.x * 256 + threadIdx.x;
    if (gid >= TBL_TOTAL) {
        int r = gid - TBL_TOTAL;
        if (r < 72) stats1[r] = 0.f;
        else if (r < 144) stats2[r - 72] = 0.f;
        return;
    }

    const float inv_ks15 = 0.19245008972987526f;  // 1/3^1.5
    const float s3   = 1.7320508075688772f;
    const float a1   = 0.35355339059327373f;  // 1/sqrt(8)
    const float a_s  = 0.2041241452319315f;   // 1/sqrt(24)
    const float a_v  = 0.17677669529663687f;  // 1/sqrt(32)
    const float a_s3 = 0.11785113019775793f;  // a_s/sqrt(3)
    const float a_v6 = 0.07216878364870322f;  // a_v/sqrt(6)

    float embC[4], embF[4];
    lattice_emb(13, embC);   // center (r=0)
    lattice_emb(22, embF);   // face   (r=1), shared by all 6 faces

    auto WC1 = [&](int c) { float s=0.f;
        #pragma unroll
        for (int b=0;b<4;b++) s += embC[b]*w1[b*256+c]; return s*inv_ks15; };
    auto WF1 = [&](int c) { float s=0.f;
        #pragma unroll
        for (int b=0;b<4;b++) s += embF[b]*w1[b*256+c]; return s*inv_ks15; };
    auto WC2 = [&](int c) { float s=0.f;
        #pragma unroll
        for (int b=0;b<4;b++) s += embC[b]*w2[b*832+c]; return s*inv_ks15; };
    auto WF2 = [&](int c) { float s=0.f;
        #pragma unroll
        for (int b=0;b<4;b++) s += embF[b]*w2[b*832+c]; return s*inv_ks15; };

    float val = 0.f;
    if (gid < 192) {                       // T1c
        int i = gid / 24, o = gid % 24;
        int c = (o < 16) ? i * 16 + o : 128 + i * 8 + (o - 16);
        val = a1 * WC1(c) + a1 * sc1[i * 24 + o];
    } else if (gid < 384) {                // T1f
        int r = gid - 192; int i = r / 24, o = r % 24;
        int c = (o < 16) ? i * 16 + o : 128 + i * 8 + (o - 16);
        val = a1 * WF1(c);
    } else if (gid < 448) {                // T1v
        int r = gid - 384; int i = r / 8, jj = r % 8;
        val = a1 * s3 * WF1(192 + i * 8 + jj);
    } else if (gid < 832) {                // T2c
        int r = gid - 448; int i = r / 24, o = r % 24;
        int c = (o < 16) ? i * 16 + o : 256 + i * 8 + (o - 16);
        val = a_s * WC2(c) + 0.25f * sc2s[i * 24 + o];
    } else if (gid < 1216) {               // T2f
        int r = gid - 832; int i = r / 24, o = r % 24;
        int c = (o < 16) ? i * 16 + o : 256 + i * 8 + (o - 16);
        val = a_s * WF2(c);
    } else if (gid < 1344) {               // T2sv
        int r = gid - 1216; int i = r / 8, jj = r % 8;
        val = a_v * s3 * WF2(384 + i * 8 + jj);
    } else if (gid < 1536) {               // T2vs
        int r = gid - 1344; int u = r / 24, o = r % 24;
        int c = (o < 16) ? 576 + u * 16 + o : 704 + u * 8 + (o - 16);
        val = a_s3 * s3 * WF2(c);
    } else if (gid < 1600) {               // T2v0c
        int r = gid - 1536; int u = r / 8, jj = r % 8;
        val = a_v * WC2(512 + u * 8 + jj) + a1 * sc2v[u * 8 + jj];
    } else if (gid < 1664) {               // T2v0f
        int r = gid - 1600; int u = r / 8, jj = r % 8;
        val = a_v * WF2(512 + u * 8 + jj);
    } else {                               // T2v1
        int r = gid - 1664; int u = r / 8, jj = r % 8;
        val = a_v6 * s3 * WF2(768 + u * 8 + jj);
    }
    T[gid] = val;
}

// ---------------------------------------------------------------------------
// helpers
// ---------------------------------------------------------------------------
__device__ inline float4 f4z() { return make_float4(0.f, 0.f, 0.f, 0.f); }
__device__ inline float4 f4add(float4 a, float4 b) {
    return make_float4(a.x+b.x, a.y+b.y, a.z+b.z, a.w+b.w); }
__device__ inline float4 f4sub(float4 a, float4 b) {
    return make_float4(a.x-b.x, a.y-b.y, a.z-b.z, a.w-b.w); }
__device__ inline float4 f4fma(float s, float4 a, float4 c) {
    return make_float4(fmaf(s,a.x,c.x), fmaf(s,a.y,c.y), fmaf(s,a.z,c.z), fmaf(s,a.w,c.w)); }
__device__ inline float f4sum(float4 a) { return a.x+a.y+a.z+a.w; }
__device__ inline float f4dot(float4 a) { return a.x*a.x+a.y*a.y+a.z*a.z+a.w*a.w; }

__device__ inline unsigned pk2(float a, float b) {   // RNE f32->bf16 pair
    unsigned ua = __float_as_uint(a);
    unsigned ub = __float_as_uint(b);
    unsigned ra = (ua + 0x7FFFu + ((ua >> 16) & 1u)) >> 16;
    unsigned rb = (ub + 0x7FFFu + ((ub >> 16) & 1u)) >> 16;
    return ra | (rb << 16);
}
__device__ inline float4 unpk_lo(uint4 p) {
    return make_float4(__uint_as_float(p.x << 16), __uint_as_float(p.y << 16),
                       __uint_as_float(p.z << 16), __uint_as_float(p.w << 16));
}
__device__ inline float4 unpk_hi(uint4 p) {
    return make_float4(__uint_as_float(p.x & 0xffff0000u), __uint_as_float(p.y & 0xffff0000u),
                       __uint_as_float(p.z & 0xffff0000u), __uint_as_float(p.w & 0xffff0000u));
}

// Load quads for c, d+-, h+- of one f32 channel row
#define LQ5(BP, C_, DM_, DP_, HM_, HP_)                                       \
    {                                                                         \
        const float* _p = (BP);                                               \
        C_  = *(const float4*)_p;                                             \
        DM_ = dmok ? *(const float4*)(_p - 4096) : f4z();                     \
        DP_ = dpok ? *(const float4*)(_p + 4096) : f4z();                     \
        HM_ = hmok ? *(const float4*)(_p -   64) : f4z();                     \
        HP_ = hpok ? *(const float4*)(_p +   64) : f4z();                     \
    }

// Packed (uint4) variant for bf16-pair rows
#define LQP(BP, C_, DM_, DP_, HM_, HP_)                                       \
    {                                                                         \
        const unsigned* _p = (BP);                                            \
        const uint4 _z = make_uint4(0u, 0u, 0u, 0u);                          \
        C_  = *(const uint4*)_p;                                              \
        DM_ = dmok ? *(const uint4*)(_p - 4096) : _z;                         \
        DP_ = dpok ? *(const uint4*)(_p + 4096) : _z;                         \
        HM_ = hmok ? *(const uint4*)(_p -   64) : _z;                         \
        HP_ = hpok ? *(const uint4*)(_p +   64) : _z;                         \
    }

// w-neighbor quads from c (in-quad shifts + cross-lane shfl at quad edges)
#define WQ(C_, WM_, WP_)                                                      \
    {                                                                         \
        float _lw = __shfl_up((C_).w, 1, 64);                                 \
        float _rw = __shfl_down((C_).x, 1, 64);                               \
        WM_ = make_float4(wL ? 0.f : _lw, (C_).x, (C_).y, (C_).z);            \
        WP_ = make_float4((C_).y, (C_).z, (C_).w, wR ? 0.f : _rw);            \
    }

// XCD-aware swizzle for 256-block grids (verified win, R18)
__device__ inline int xcd_swz(int bx) { return (bx & 7) * 32 + (bx >> 3); }

// ---------------------------------------------------------------------------
// conv1: x(8,64^3) -> zpre1(48,64^3). Unchanged from R18 (verified).
// ---------------------------------------------------------------------------
__global__ __launch_bounds__(256, 2) void conv1_kernel(const float* __restrict__ x,
                                                       const float* __restrict__ Tg,
                                                       float* __restrict__ out,
                                                       float* __restrict__ stats) {
    __shared__ float T[448];
    __shared__ float red[4][48];
    for (int t = threadIdx.x; t < 448; t += 256) T[t] = Tg[t];
    __syncthreads();

    const int ohalf = blockIdx.y;
    int idx = xcd_swz(blockIdx.x) * 1024 + threadIdx.x * 4;
    int w0 = idx & 63, h = (idx >> 6) & 63, d = idx >> 12;
    bool dmok = d > 0, dpok = d < 63, hmok = h > 0, hpok = h < 63;
    bool wL = (w0 == 0), wR = (w0 == 60);

    float4 acc[24];
    #pragma unroll
    for (int o = 0; o < 24; o++) acc[o] = f4z();

    float4 nc, ndm, ndp, nhm, nhp;
    LQ5(x + idx, nc, ndm, ndp, nhm, nhp);

    if (ohalf == 0) {
        #pragma unroll 1
        for (int i = 0; i < 8; i++) {
            float4 c = nc, dmq = ndm, dpq = ndp, hmq = nhm, hpq = nhp;
            if (i < 7) LQ5(x + (i + 1) * N3 + idx, nc, ndm, ndp, nhm, nhp);
            float4 wmq, wpq; WQ(c, wmq, wpq);
            float4 S = f4add(f4add(f4add(dmq, dpq), f4add(hmq, hpq)), f4add(wmq, wpq));
            const float* tc = &T[i * 24];
            const float* tf = &T[192 + i * 24];
            #pragma unroll
            for (int o = 0; o < 24; o++)
                acc[o] = f4fma(tc[o], c, f4fma(tf[o], S, acc[o]));
        }
    } else {
        #pragma unroll 1
        for (int i = 0; i < 8; i++) {
            float4 c = nc, dmq = ndm, dpq = ndp, hmq = nhm, hpq = nhp;
            if (i < 7) LQ5(x + (i + 1) * N3 + idx, nc, ndm, ndp, nhm, nhp);
            float4 wmq, wpq; WQ(c, wmq, wpq);
            float4 Dd = f4sub(dpq, dmq), Dh = f4sub(hpq, hmq), Dw = f4sub(wpq, wmq);
            const float* tv = &T[384 + i * 8];
            #pragma unroll
            for (int jj = 0; jj < 8; jj++) {
                float wv = tv[jj];
                acc[jj * 3 + 0] = f4fma(wv, Dd, acc[jj * 3 + 0]);
                acc[jj * 3 + 1] = f4fma(wv, Dh, acc[jj * 3 + 1]);
                acc[jj * 3 + 2] = f4fma(wv, Dw, acc[jj * 3 + 2]);
            }
        }
    }

    int obase = ohalf * 24;
    #pragma unroll
    for (int o = 0; o < 24; o++)
        *(float4*)(out + (obase + o) * N3 + idx) = acc[o];

    int lane = threadIdx.x & 63, wvx = threadIdx.x >> 6;
    if (ohalf == 0) {
        #pragma unroll
        for (int q = 0; q < 48; q++) {
            float val = (q < 24) ? f4sum(acc[q]) : f4dot(acc[q - 24]);
            #pragma unroll
            for (int mq = 32; mq >= 1; mq >>= 1) val += __shfl_xor(val, mq, 64);
            if (lane == 0) red[wvx][q] = val;
        }
        __syncthreads();
        if (threadIdx.x < 48)
            atomicAdd(&stats[threadIdx.x],
                      red[0][threadIdx.x] + red[1][threadIdx.x] +
                      red[2][threadIdx.x] + red[3][threadIdx.x]);
    } else {
        #pragma unroll
        for (int q = 0; q < 24; q++) {
            float val = f4dot(acc[q]);
            #pragma unroll
            for (int mq = 32; mq >= 1; mq >>= 1) val += __shfl_xor(val, mq, 64);
            if (lane == 0) red[wvx][q] = val;
        }
        __syncthreads();
        if (threadIdx.x < 24)
            atomicAdd(&stats[48 + threadIdx.x],
                      red[0][threadIdx.x] + red[1][threadIdx.x] +
                      red[2][threadIdx.x] + red[3][threadIdx.x]);
    }
}

// ---------------------------------------------------------------------------
// bn_gate_pack: zpre1(48ch f32) -> ypk(8 pair-planes, bf16x2) + yv(24ch f32)
// ---------------------------------------------------------------------------
__global__ __launch_bounds__(256) void bn_gate_pack_kernel(
        const float* __restrict__ zp, const float* __restrict__ stats,
        const float* __restrict__ wsc, const float* __restrict__ bsc,
        const float* __restrict__ wvc,
        unsigned* __restrict__ ypk, float* __restrict__ yv) {
    __shared__ float sb[56];
    if (threadIdx.x < 32) {
        int t = threadIdx.x;
        const float invN = 1.0f / 262144.0f;
        if (t < 24) {
            float mu = stats[t] * invN;
            float var = stats[24 + t] * invN - mu * mu;
            float inv = rsqrtf(var + 1e-5f);
            sb[t] = wsc[t] * inv;
            sb[24 + t] = bsc[t] - mu * wsc[t] * inv;
        } else {
            int u = t - 24;
            float s2 = stats[48 + u * 3] + stats[48 + u * 3 + 1] + stats[48 + u * 3 + 2];
            sb[48 + u] = wvc[u] * rsqrtf(s2 * invN + 1e-5f);
        }
    }
    __syncthreads();

    int idx = (blockIdx.x * 256 + threadIdx.x) * 2;
    float2 g[8];
    #pragma unroll
    for (int u = 0; u < 8; u++) {
        float2 v = *(const float2*)(zp + (16 + u) * N3 + idx);
        float sc = sb[16 + u], bi = sb[40 + u];
        g[u].x = 1.0f / (1.0f + expf(-(v.x * sc + bi)));
        g[u].y = 1.0f / (1.0f + expf(-(v.y * sc + bi)));
    }
    // scalar pairs: relu then pack (ch 2p low, ch 2p+1 high)
    #pragma unroll
    for (int p = 0; p < 8; p++) {
        float2 v0 = *(const float2*)(zp + (2 * p) * N3 + idx);
        float2 v1 = *(const float2*)(zp + (2 * p + 1) * N3 + idx);
        float r0x = fmaxf(v0.x * sb[2*p] + sb[24 + 2*p], 0.f);
        float r0y = fmaxf(v0.y * sb[2*p] + sb[24 + 2*p], 0.f);
        float r1x = fmaxf(v1.x * sb[2*p+1] + sb[24 + 2*p+1], 0.f);
        float r1y = fmaxf(v1.y * sb[2*p+1] + sb[24 + 2*p+1], 0.f);
        uint2 st;
        st.x = pk2(r0x, r1x);
        st.y = pk2(r0y, r1y);
        *(uint2*)(ypk + p * N3 + idx) = st;
    }
    // vector comps: gated f32
    #pragma unroll
    for (int u = 0; u < 8; u++) {
        float sv = sb[48 + u];
        #pragma unroll
        for (int m = 0; m < 3; m++) {
            float2 v = *(const float2*)(zp + (24 + u * 3 + m) * N3 + idx);
            float2 r;
            r.x = v.x * sv * g[u].x;
            r.y = v.y * sv * g[u].y;
            *(float2*)(yv + (u * 3 + m) * N3 + idx) = r;
        }
    }
}

// ---------------------------------------------------------------------------
// conv2: ypk(bf16 pairs) + yv(f32) -> zpre2(48,64^3). Scalar taps packed.
// ---------------------------------------------------------------------------
__global__ __launch_bounds__(256, 2) void conv2_kernel(
        const unsigned* __restrict__ ypk, const float* __restrict__ yv,
        const float* __restrict__ Tg, float* __restrict__ out,
        float* __restrict__ stats) {
    __shared__ float T[1280];
    __shared__ float red[4][48];
    for (int t = threadIdx.x; t < 1280; t += 256) T[t] = Tg[448 + t];
    __syncthreads();

    const int ohalf = blockIdx.y;
    int idx = xcd_swz(blockIdx.x) * 1024 + threadIdx.x * 4;
    int w0 = idx & 63, h = (idx >> 6) & 63, d = idx >> 12;
    bool dmok = d > 0, dpok = d < 63, hmok = h > 0, hpok = h < 63;
    bool wL = (w0 == 0), wR = (w0 == 60);

    float4 acc[24];
    #pragma unroll
    for (int o = 0; o < 24; o++) acc[o] = f4z();

    // ---- scalar rows via bf16 pairs (both halves need them) ----
    {
        uint4 pc, pdm, pdp, phm, php;
        LQP(ypk + idx, pc, pdm, pdp, phm, php);
        #pragma unroll 1
        for (int p = 0; p < 8; p++) {
            uint4 qc = pc, qdm = pdm, qdp = pdp, qhm = phm, qhp = php;
            if (p < 7) LQP(ypk + (p + 1) * N3 + idx, pc, pdm, pdp, phm, php);
            // row i0 = 2p (low halves)
            {
                float4 c   = unpk_lo(qc);
                float4 dmq = unpk_lo(qdm), dpq = unpk_lo(qdp);
                float4 hmq = unpk_lo(qhm), hpq = unpk_lo(qhp);
                float4 wmq, wpq; WQ(c, wmq, wpq);
                int i = 2 * p;
                if (ohalf == 0) {
                    float4 S = f4add(f4add(f4add(dmq, dpq), f4add(hmq, hpq)), f4add(wmq, wpq));
                    const float* tc = &T[i * 24];
                    const float* tf = &T[384 + i * 24];
                    #pragma unroll
                    for (int o = 0; o < 24; o++)
                        acc[o] = f4fma(tc[o], c, f4fma(tf[o], S, acc[o]));
                } else {
                    float4 Dd = f4sub(dpq, dmq), Dh = f4sub(hpq, hmq), Dw = f4sub(wpq, wmq);
                    const float* tv = &T[768 + i * 8];
                    #pragma unroll
                    for (int jj = 0; jj < 8; jj++) {
                        float wv = tv[jj];
                        acc[jj * 3 + 0] = f4fma(wv, Dd, acc[jj * 3 + 0]);
                        acc[jj * 3 + 1] = f4fma(wv, Dh, acc[jj * 3 + 1]);
                        acc[jj * 3 + 2] = f4fma(wv, Dw, acc[jj * 3 + 2]);
                    }
                }
            }
            // row i1 = 2p+1 (high halves)
            {
                float4 c   = unpk_hi(qc);
                float4 dmq = unpk_hi(qdm), dpq = unpk_hi(qdp);
                float4 hmq = unpk_hi(qhm), hpq = unpk_hi(qhp);
                float4 wmq, wpq; WQ(c, wmq, wpq);
                int i = 2 * p + 1;
                if (ohalf == 0) {
                    float4 S = f4add(f4add(f4add(dmq, dpq), f4add(hmq, hpq)), f4add(wmq, wpq));
                    const float* tc = &T[i * 24];
                    const float* tf = &T[384 + i * 24];
                    #pragma unroll
                    for (int o = 0; o < 24; o++)
                        acc[o] = f4fma(tc[o], c, f4fma(tf[o], S, acc[o]));
                } else {
                    float4 Dd = f4sub(dpq, dmq), Dh = f4sub(hpq, hmq), Dw = f4sub(wpq, wmq);
                    const float* tv = &T[768 + i * 8];
                    #pragma unroll
                    for (int jj = 0; jj < 8; jj++) {
                        float wv = tv[jj];
                        acc[jj * 3 + 0] = f4fma(wv, Dd, acc[jj * 3 + 0]);
                        acc[jj * 3 + 1] = f4fma(wv, Dh, acc[jj * 3 + 1]);
                        acc[jj * 3 + 2] = f4fma(wv, Dw, acc[jj * 3 + 2]);
                    }
                }
            }
        }
    }

    // ---- vector rows (f32 planar in yv; comp index = y ch - 16) ----
    if (ohalf == 0) {
        #pragma unroll 1
        for (int u = 0; u < 8; u++) {
            const float* b0 = yv + (u * 3) * N3 + idx;
            float4 qdm = dmok ? *(const float4*)(b0 - 4096) : f4z();
            float4 qdp = dpok ? *(const float4*)(b0 + 4096) : f4z();
            float4 qhm = hmok ? *(const float4*)(b0 + N3 - 64) : f4z();
            float4 qhp = hpok ? *(const float4*)(b0 + N3 + 64) : f4z();
            float4 c2  = *(const float4*)(b0 + 2 * N3);
            float4 wmq, wpq; WQ(c2, wmq, wpq);
            float4 Dsum = f4add(f4add(f4sub(qdp, qdm), f4sub(qhp, qhm)), f4sub(wpq, wmq));
            const float* tvs = &T[896 + u * 24];
            #pragma unroll
            for (int o = 0; o < 24; o++)
                acc[o] = f4fma(tvs[o], Dsum, acc[o]);
        }
    } else {
        #pragma unroll 1
        for (int u = 0; u < 8; u++) {
            const float* t0c = &T[1088 + u * 8];
            const float* t0f = &T[1152 + u * 8];
            const float* tv1 = &T[1216 + u * 8];
            {   // m=0
                float4 c, dmq, dpq, hmq, hpq;
                LQ5(yv + (u * 3 + 0) * N3 + idx, c, dmq, dpq, hmq, hpq);
                float4 wmq, wpq; WQ(c, wmq, wpq);
                float4 S = f4add(f4add(f4add(dmq, dpq), f4add(hmq, hpq)), f4add(wmq, wpq));
                float4 Dh = f4sub(hpq, hmq), Dw = f4sub(wpq, wmq);
                #pragma unroll
                for (int jj = 0; jj < 8; jj++) {
                    float k1 = tv1[jj];
                    acc[jj * 3 + 0] = f4fma(t0c[jj], c, f4fma(t0f[jj], S, acc[jj * 3 + 0]));
                    acc[jj * 3 + 2] = f4fma(k1, Dh, acc[jj * 3 + 2]);
                    acc[jj * 3 + 1] = f4fma(-k1, Dw, acc[jj * 3 + 1]);
                }
            }
            {   // m=1
                float4 c, dmq, dpq, hmq, hpq;
                LQ5(yv + (u * 3 + 1) * N3 + idx, c, dmq, dpq, hmq, hpq);
                float4 wmq, wpq; WQ(c, wmq, wpq);
                float4 S = f4add(f4add(f4add(dmq, dpq), f4add(hmq, hpq)), f4add(wmq, wpq));
                float4 Dd = f4sub(dpq, dmq), Dw = f4sub(wpq, wmq);
                #pragma unroll
                for (int jj = 0; jj < 8; jj++) {
                    float k1 = tv1[jj];
                    acc[jj * 3 + 1] = f4fma(t0c[jj], c, f4fma(t0f[jj], S, acc[jj * 3 + 1]));
                    acc[jj * 3 + 0] = f4fma(k1, Dw, acc[jj * 3 + 0]);
                    acc[jj * 3 + 2] = f4fma(-k1, Dd, acc[jj * 3 + 2]);
                }
            }
            {   // m=2
                float4 c, dmq, dpq, hmq, hpq;
                LQ5(yv + (u * 3 + 2) * N3 + idx, c, dmq, dpq, hmq, hpq);
                float4 wmq, wpq; WQ(c, wmq, wpq);
                float4 S = f4add(f4add(f4add(dmq, dpq), f4add(hmq, hpq)), f4add(wmq, wpq));
                float4 Dd = f4sub(dpq, dmq), Dh = f4sub(hpq, hmq);
                #pragma unroll
                for (int jj = 0; jj < 8; jj++) {
                    float k1 = tv1[jj];
                    acc[jj * 3 + 2] = f4fma(t0c[jj], c, f4fma(t0f[jj], S, acc[jj * 3 + 2]));
                    acc[jj * 3 + 1] = f4fma(k1, Dd, acc[jj * 3 + 1]);
                    acc[jj * 3 + 0] = f4fma(-k1, Dh, acc[jj * 3 + 0]);
                }
            }
        }
    }

    int obase = ohalf * 24;
    #pragma unroll
    for (int o = 0; o < 24; o++)
        *(float4*)(out + (obase + o) * N3 + idx) = acc[o];

    int lane = threadIdx.x & 63, wvx = threadIdx.x >> 6;
    if (ohalf == 0) {
        #pragma unroll
        for (int q = 0; q < 48; q++) {
            float val = (q < 24) ? f4sum(acc[q]) : f4dot(acc[q - 24]);
            #pragma unroll
            for (int mq = 32; mq >= 1; mq >>= 1) val += __shfl_xor(val, mq, 64);
            if (lane == 0) red[wvx][q] = val;
        }
        __syncthreads();
        if (threadIdx.x < 48)
            atomicAdd(&stats[threadIdx.x],
                      red[0][threadIdx.x] + red[1][threadIdx.x] +
                      red[2][threadIdx.x] + red[3][threadIdx.x]);
    } else {
        #pragma unroll
        for (int q = 0; q < 24; q++) {
            float val = f4dot(acc[q]);
            #pragma unroll
            for (int mq = 32; mq >= 1; mq >>= 1) val += __shfl_xor(val, mq, 64);
            if (lane == 0) red[wvx][q] = val;
        }
        __syncthreads();
        if (threadIdx.x < 24)
            atomicAdd(&stats[48 + threadIdx.x],
                      red[0][threadIdx.x] + red[1][threadIdx.x] +
                      red[2][threadIdx.x] + red[3][threadIdx.x]);
    }
}

// ---------------------------------------------------------------------------
// bn_gate (pass 2, unchanged): zpre2(48ch) -> out(40ch), float2/thread
// ---------------------------------------------------------------------------
__global__ __launch_bounds__(256) void bn_gate_kernel(const float* __restrict__ zp,
                                                      const float* __restrict__ stats,
                                                      const float* __restrict__ wsc,
                                                      const float* __restrict__ bsc,
                                                      const float* __restrict__ wvc,
                                                      float* __restrict__ out) {
    __shared__ float sb[56];
    if (threadIdx.x < 32) {
        int t = threadIdx.x;
        const float invN = 1.0f / 262144.0f;
        if (t < 24) {
            float mu = stats[t] * invN;
            float var = stats[24 + t] * invN - mu * mu;
            float inv = rsqrtf(var + 1e-5f);
            sb[t] = wsc[t] * inv;
            sb[24 + t] = bsc[t] - mu * wsc[t] * inv;
        } else {
            int u = t - 24;
            float s2 = stats[48 + u * 3] + stats[48 + u * 3 + 1] + stats[48 + u * 3 + 2];
            sb[48 + u] = wvc[u] * rsqrtf(s2 * invN + 1e-5f);
        }
    }
    __syncthreads();

    int idx = (blockIdx.x * 256 + threadIdx.x) * 2;
    float2 g[8];
    #pragma unroll
    for (int u = 0; u < 8; u++) {
        float2 v = *(const float2*)(zp + (16 + u) * N3 + idx);
        float sc = sb[16 + u], bi = sb[40 + u];
        g[u].x = 1.0f / (1.0f + expf(-(v.x * sc + bi)));
        g[u].y = 1.0f / (1.0f + expf(-(v.y * sc + bi)));
    }
    #pragma unroll
    for (int c = 0; c < 16; c++) {
        float2 v = *(const float2*)(zp + c * N3 + idx);
        float sc = sb[c], bi = sb[24 + c];
        float2 r;
        r.x = fmaxf(v.x * sc + bi, 0.f);
        r.y = fmaxf(v.y * sc + bi, 0.f);
        *(float2*)(out + c * N3 + idx) = r;
    }
    #pragma unroll
    for (int u = 0; u < 8; u++) {
        float sv = sb[48 + u];
        #pragma unroll
        for (int m = 0; m < 3; m++) {
            float2 v = *(const float2*)(zp + (24 + u * 3 + m) * N3 + idx);
            float2 r;
            r.x = v.x * sv * g[u].x;
            r.y = v.y * sv * g[u].y;
            *(float2*)(out + (16 + u * 3 + m) * N3 + idx) = r;
        }
    }
}

// ---------------------------------------------------------------------------
extern "C" void kernel_launch(void* const* d_in, const int* in_sizes, int n_in,
                              void* d_out, int out_size, void* d_ws, size_t ws_size,
                              hipStream_t stream) {
    const float* x      = (const float*)d_in[0];
    const float* w1     = (const float*)d_in[1];
    const float* sc1    = (const float*)d_in[2];
    const float* w2     = (const float*)d_in[3];
    const float* sc2s   = (const float*)d_in[4];
    const float* sc2v   = (const float*)d_in[5];
    const float* bn1_ws = (const float*)d_in[6];
    const float* bn1_bs = (const float*)d_in[7];
    const float* bn1_wv = (const float*)d_in[8];
    const float* bn2_ws = (const float*)d_in[9];
    const float* bn2_bs = (const float*)d_in[10];
    const float* bn2_wv = (const float*)d_in[11];
    float* out = (float*)d_out;
    char* ws = (char*)d_ws;

    float*    Tg     = (float*)(ws + 0);        // 1728 floats
    float*    stats1 = (float*)(ws + 8192);
    float*    stats2 = (float*)(ws + 8192 + 512);
    float*    bufA   = (float*)(ws + 262144);               // zpre 48ch, 50.3 MB
    unsigned* ypk    = (unsigned*)(ws + 262144 + 50331648); // 8 pair-planes, 8.4 MB
    float*    yv     = (float*)(ws + 262144 + 50331648 + 8388608); // 24ch, 25.2 MB
    // total ~84.1 MB < ws_size (256 MiB per harness poison fill)

    hipLaunchKernelGGL(build_tables_kernel, dim3(8), dim3(256), 0, stream,
                       w1, sc1, w2, sc2s, sc2v, Tg, stats1, stats2);
    hipLaunchKernelGGL(conv1_kernel, dim3(256, 2), dim3(256), 0, stream, x, Tg, bufA, stats1);
    hipLaunchKernelGGL(bn_gate_pack_kernel, dim3(512), dim3(256), 0, stream,
                       bufA, stats1, bn1_ws, bn1_bs, bn1_wv, ypk, yv);
    hipLaunchKernelGGL(conv2_kernel, dim3(256, 2), dim3(256), 0, stream,
                       ypk, yv, Tg, bufA, stats2);
    hipLaunchKernelGGL(bn_gate_kernel, dim3(512), dim3(256), 0, stream,
                       bufA, stats2, bn2_ws, bn2_bs, bn2_wv, out);
}

// Round 20
// 108.275 us; speedup vs baseline: 1.9509x; 1.9509x over previous
//
#include <hip/hip_runtime.h>
#include <math.h>

#define N3 262144           // 64^3

// ===========================================================================
// FINAL (R18-verified, 109.2us): derived-feature 7-point stencil formulation.
// - emb==0 for r=sqrt2/sqrt3 -> 27-tap conv is exactly a 7-point stencil;
//   per input row only c (center), S (6-face sum), D_A (axis diffs) matter.
//   5.4x FLOP cut vs direct conv; skips folded into tables.
// - float4 4pts/thread, 2-way output-channel split, 256-thread blocks
//   (16 w-rows -> halo reuse), XCD-aware swizzle (d-planes stay on one XCD).
// - BN stats fused into conv via shuffle-reduce + atomics; finalize fused
//   into gate kernel. 5 dispatches total.
// Closed avenues (measured): unroll depth (R7/R8), LDS staging (R9),
// shfl+prefetch (R10), float2/ch-x4 wave-count (R13/R14), A/B pipelining
// (R12), cooperative fusion (R16/R17: spills acc across grid.sync),
// bf16 packing (R19: +40 VGPR -> spill). Latency-bound at 2 waves/SIMD.
// ===========================================================================

// Table layout (floats):
// conv1 (448): T1c[8][24]@0, T1f[8][24]@192, T1v[8][8]@384
// conv2 (1280)@448: T2c[16][24]@+0, T2f[16][24]@+384, T2sv[16][8]@+768,
//   T2vs[8][24]@+896, T2v0c[8][8]@+1088, T2v0f[8][8]@+1152, T2v1[8][8]@+1216
#define TBL_TOTAL 1728

__device__ inline void lattice_emb(int p, float* embr) {
    int i = p / 9, j = (p / 3) % 3, k = p % 3;
    float gx = (float)(i - 1), gy = (float)(j - 1), gz = (float)(k - 1);
    float r = sqrtf(gx * gx + gy * gy + gz * gz);
    const float centers[4] = {0.f, 0.33333334f, 0.6666667f, 1.f};
    const float step = 0.33333334f;
    #pragma unroll
    for (int b = 0; b < 4; b++) {
        float dd = (r - centers[b]) / step;
        float e = 0.f;
        if (fabsf(dd) < 1.f)
            e = 1.14136f * expf(2.f) * expf(-1.f / fmaxf(1.f - dd * dd, 1e-9f));
        embr[b] = e;
    }
}

// Also zeroes the BN stats buffers (threads TBL_TOTAL..TBL_TOTAL+143).
__global__ __launch_bounds__(256) void build_tables_kernel(
        const float* __restrict__ w1,  const float* __restrict__ sc1,
        const float* __restrict__ w2,  const float* __restrict__ sc2s,
        const float* __restrict__ sc2v, float* __restrict__ T,
        float* __restrict__ stats1, float* __restrict__ stats2) {
    int gid = blockIdx.x * 256 + threadIdx.x;
    if (gid >= TBL_TOTAL) {
        int r = gid - TBL_TOTAL;
        if (r < 72) stats1[r] = 0.f;
        else if (r < 144) stats2[r - 72] = 0.f;
        return;
    }

    const float inv_ks15 = 0.19245008972987526f;  // 1/3^1.5
    const float s3   = 1.7320508075688772f;
    const float a1   = 0.35355339059327373f;  // 1/sqrt(8)
    const float a_s  = 0.2041241452319315f;   // 1/sqrt(24)
    const float a_v  = 0.17677669529663687f;  // 1/sqrt(32)
    const float a_s3 = 0.11785113019775793f;  // a_s/sqrt(3)
    const float a_v6 = 0.07216878364870322f;  // a_v/sqrt(6)

    float embC[4], embF[4];
    lattice_emb(13, embC);   // center (r=0)
    lattice_emb(22, embF);   // face   (r=1), shared by all 6 faces

    auto WC1 = [&](int c) { float s=0.f;
        #pragma unroll
        for (int b=0;b<4;b++) s += embC[b]*w1[b*256+c]; return s*inv_ks15; };
    auto WF1 = [&](int c) { float s=0.f;
        #pragma unroll
        for (int b=0;b<4;b++) s += embF[b]*w1[b*256+c]; return s*inv_ks15; };
    auto WC2 = [&](int c) { float s=0.f;
        #pragma unroll
        for (int b=0;b<4;b++) s += embC[b]*w2[b*832+c]; return s*inv_ks15; };
    auto WF2 = [&](int c) { float s=0.f;
        #pragma unroll
        for (int b=0;b<4;b++) s += embF[b]*w2[b*832+c]; return s*inv_ks15; };

    float val = 0.f;
    if (gid < 192) {                       // T1c
        int i = gid / 24, o = gid % 24;
        int c = (o < 16) ? i * 16 + o : 128 + i * 8 + (o - 16);
        val = a1 * WC1(c) + a1 * sc1[i * 24 + o];
    } else if (gid < 384) {                // T1f
        int r = gid - 192; int i = r / 24, o = r % 24;
        int c = (o < 16) ? i * 16 + o : 128 + i * 8 + (o - 16);
        val = a1 * WF1(c);
    } else if (gid < 448) {                // T1v
        int r = gid - 384; int i = r / 8, jj = r % 8;
        val = a1 * s3 * WF1(192 + i * 8 + jj);
    } else if (gid < 832) {                // T2c
        int r = gid - 448; int i = r / 24, o = r % 24;
        int c = (o < 16) ? i * 16 + o : 256 + i * 8 + (o - 16);
        val = a_s * WC2(c) + 0.25f * sc2s[i * 24 + o];
    } else if (gid < 1216) {               // T2f
        int r = gid - 832; int i = r / 24, o = r % 24;
        int c = (o < 16) ? i * 16 + o : 256 + i * 8 + (o - 16);
        val = a_s * WF2(c);
    } else if (gid < 1344) {               // T2sv
        int r = gid - 1216; int i = r / 8, jj = r % 8;
        val = a_v * s3 * WF2(384 + i * 8 + jj);
    } else if (gid < 1536) {               // T2vs
        int r = gid - 1344; int u = r / 24, o = r % 24;
        int c = (o < 16) ? 576 + u * 16 + o : 704 + u * 8 + (o - 16);
        val = a_s3 * s3 * WF2(c);
    } else if (gid < 1600) {               // T2v0c
        int r = gid - 1536; int u = r / 8, jj = r % 8;
        val = a_v * WC2(512 + u * 8 + jj) + a1 * sc2v[u * 8 + jj];
    } else if (gid < 1664) {               // T2v0f
        int r = gid - 1600; int u = r / 8, jj = r % 8;
        val = a_v * WF2(512 + u * 8 + jj);
    } else {                               // T2v1
        int r = gid - 1664; int u = r / 8, jj = r % 8;
        val = a_v6 * s3 * WF2(768 + u * 8 + jj);
    }
    T[gid] = val;
}

// ---------------------------------------------------------------------------
// float4 helpers
// ---------------------------------------------------------------------------
__device__ inline float4 f4z() { return make_float4(0.f, 0.f, 0.f, 0.f); }
__device__ inline float4 f4add(float4 a, float4 b) {
    return make_float4(a.x+b.x, a.y+b.y, a.z+b.z, a.w+b.w); }
__device__ inline float4 f4sub(float4 a, float4 b) {
    return make_float4(a.x-b.x, a.y-b.y, a.z-b.z, a.w-b.w); }
__device__ inline float4 f4fma(float s, float4 a, float4 c) {
    return make_float4(fmaf(s,a.x,c.x), fmaf(s,a.y,c.y), fmaf(s,a.z,c.z), fmaf(s,a.w,c.w)); }
__device__ inline float f4sum(float4 a) { return a.x+a.y+a.z+a.w; }
__device__ inline float f4dot(float4 a) { return a.x*a.x+a.y*a.y+a.z*a.z+a.w*a.w; }

// Load quads for c, d+-, h+- of one channel row
#define LQ5(BP, C_, DM_, DP_, HM_, HP_)                                       \
    {                                                                         \
        const float* _p = (BP);                                               \
        C_  = *(const float4*)_p;                                             \
        DM_ = dmok ? *(const float4*)(_p - 4096) : f4z();                     \
        DP_ = dpok ? *(const float4*)(_p + 4096) : f4z();                     \
        HM_ = hmok ? *(const float4*)(_p -   64) : f4z();                     \
        HP_ = hpok ? *(const float4*)(_p +   64) : f4z();                     \
    }

// w-neighbor quads from c (in-quad shifts + cross-lane shfl at quad edges)
#define WQ(C_, WM_, WP_)                                                      \
    {                                                                         \
        float _lw = __shfl_up((C_).w, 1, 64);                                 \
        float _rw = __shfl_down((C_).x, 1, 64);                               \
        WM_ = make_float4(wL ? 0.f : _lw, (C_).x, (C_).y, (C_).z);            \
        WP_ = make_float4((C_).y, (C_).z, (C_).w, wR ? 0.f : _rw);            \
    }

// XCD-aware swizzle for 256-block grids: 8 XCDs x 32 contiguous blocks.
// Contiguous d-planes stay on one XCD -> d+-1 taps hit that XCD's L2.
__device__ inline int xcd_swz(int bx) { return (bx & 7) * 32 + (bx >> 3); }

// ---------------------------------------------------------------------------
// conv1: x(8,64^3) -> ypre(48,64^3). 4 pts/thread, channel-half split,
// 256-thread blocks (16 w-rows), XCD swizzle.
// ---------------------------------------------------------------------------
__global__ __launch_bounds__(256, 2) void conv1_kernel(const float* __restrict__ x,
                                                       const float* __restrict__ Tg,
                                                       float* __restrict__ out,
                                                       float* __restrict__ stats) {
    __shared__ float T[448];
    __shared__ float red[4][48];
    for (int t = threadIdx.x; t < 448; t += 256) T[t] = Tg[t];
    __syncthreads();

    const int ohalf = blockIdx.y;
    int idx = xcd_swz(blockIdx.x) * 1024 + threadIdx.x * 4;
    int w0 = idx & 63, h = (idx >> 6) & 63, d = idx >> 12;
    bool dmok = d > 0, dpok = d < 63, hmok = h > 0, hpok = h < 63;
    bool wL = (w0 == 0), wR = (w0 == 60);

    float4 acc[24];
    #pragma unroll
    for (int o = 0; o < 24; o++) acc[o] = f4z();

    float4 nc, ndm, ndp, nhm, nhp;
    LQ5(x + idx, nc, ndm, ndp, nhm, nhp);

    if (ohalf == 0) {
        #pragma unroll 1
        for (int i = 0; i < 8; i++) {
            float4 c = nc, dmq = ndm, dpq = ndp, hmq = nhm, hpq = nhp;
            if (i < 7) LQ5(x + (i + 1) * N3 + idx, nc, ndm, ndp, nhm, nhp);
            float4 wmq, wpq; WQ(c, wmq, wpq);
            float4 S = f4add(f4add(f4add(dmq, dpq), f4add(hmq, hpq)), f4add(wmq, wpq));
            const float* tc = &T[i * 24];
            const float* tf = &T[192 + i * 24];
            #pragma unroll
            for (int o = 0; o < 24; o++)
                acc[o] = f4fma(tc[o], c, f4fma(tf[o], S, acc[o]));
        }
    } else {
        #pragma unroll 1
        for (int i = 0; i < 8; i++) {
            float4 c = nc, dmq = ndm, dpq = ndp, hmq = nhm, hpq = nhp;
            if (i < 7) LQ5(x + (i + 1) * N3 + idx, nc, ndm, ndp, nhm, nhp);
            float4 wmq, wpq; WQ(c, wmq, wpq);
            float4 Dd = f4sub(dpq, dmq), Dh = f4sub(hpq, hmq), Dw = f4sub(wpq, wmq);
            const float* tv = &T[384 + i * 8];
            #pragma unroll
            for (int jj = 0; jj < 8; jj++) {
                float wv = tv[jj];
                acc[jj * 3 + 0] = f4fma(wv, Dd, acc[jj * 3 + 0]);
                acc[jj * 3 + 1] = f4fma(wv, Dh, acc[jj * 3 + 1]);
                acc[jj * 3 + 2] = f4fma(wv, Dw, acc[jj * 3 + 2]);
            }
        }
    }

    int obase = ohalf * 24;
    #pragma unroll
    for (int o = 0; o < 24; o++)
        *(float4*)(out + (obase + o) * N3 + idx) = acc[o];

    // fused BN partial stats
    int lane = threadIdx.x & 63, wvx = threadIdx.x >> 6;
    if (ohalf == 0) {
        #pragma unroll
        for (int q = 0; q < 48; q++) {
            float val = (q < 24) ? f4sum(acc[q]) : f4dot(acc[q - 24]);
            #pragma unroll
            for (int mq = 32; mq >= 1; mq >>= 1) val += __shfl_xor(val, mq, 64);
            if (lane == 0) red[wvx][q] = val;
        }
        __syncthreads();
        if (threadIdx.x < 48)
            atomicAdd(&stats[threadIdx.x],
                      red[0][threadIdx.x] + red[1][threadIdx.x] +
                      red[2][threadIdx.x] + red[3][threadIdx.x]);
    } else {
        #pragma unroll
        for (int q = 0; q < 24; q++) {
            float val = f4dot(acc[q]);
            #pragma unroll
            for (int mq = 32; mq >= 1; mq >>= 1) val += __shfl_xor(val, mq, 64);
            if (lane == 0) red[wvx][q] = val;
        }
        __syncthreads();
        if (threadIdx.x < 24)
            atomicAdd(&stats[48 + threadIdx.x],
                      red[0][threadIdx.x] + red[1][threadIdx.x] +
                      red[2][threadIdx.x] + red[3][threadIdx.x]);
    }
}

// ---------------------------------------------------------------------------
// conv2: y(40,64^3) -> zpre(48,64^3). 4 pts/thread, channel-half split,
// 256-thread blocks (16 w-rows), XCD swizzle.
// ---------------------------------------------------------------------------
__global__ __launch_bounds__(256, 2) void conv2_kernel(const float* __restrict__ y,
                                                       const float* __restrict__ Tg,
                                                       float* __restrict__ out,
                                                       float* __restrict__ stats) {
    __shared__ float T[1280];
    __shared__ float red[4][48];
    for (int t = threadIdx.x; t < 1280; t += 256) T[t] = Tg[448 + t];
    __syncthreads();

    const int ohalf = blockIdx.y;
    int idx = xcd_swz(blockIdx.x) * 1024 + threadIdx.x * 4;
    int w0 = idx & 63, h = (idx >> 6) & 63, d = idx >> 12;
    bool dmok = d > 0, dpok = d < 63, hmok = h > 0, hpok = h < 63;
    bool wL = (w0 == 0), wR = (w0 == 60);

    float4 acc[24];
    #pragma unroll
    for (int o = 0; o < 24; o++) acc[o] = f4z();

    if (ohalf == 0) {
        // ---- scalar rows: c,S -> tc/tf ----
        float4 nc, ndm, ndp, nhm, nhp;
        LQ5(y + idx, nc, ndm, ndp, nhm, nhp);
        #pragma unroll 1
        for (int i = 0; i < 16; i++) {
            float4 c = nc, dmq = ndm, dpq = ndp, hmq = nhm, hpq = nhp;
            if (i < 15) LQ5(y + (i + 1) * N3 + idx, nc, ndm, ndp, nhm, nhp);
            float4 wmq, wpq; WQ(c, wmq, wpq);
            float4 S = f4add(f4add(f4add(dmq, dpq), f4add(hmq, hpq)), f4add(wmq, wpq));
            const float* tc = &T[i * 24];
            const float* tf = &T[384 + i * 24];
            #pragma unroll
            for (int o = 0; o < 24; o++)
                acc[o] = f4fma(tc[o], c, f4fma(tf[o], S, acc[o]));
        }
        // ---- vector rows: only Dsum needed (divergence) ----
        #pragma unroll 1
        for (int u = 0; u < 8; u++) {
            const float* b0 = y + (16 + u * 3) * N3 + idx;
            float4 qdm = dmok ? *(const float4*)(b0 - 4096) : f4z();
            float4 qdp = dpok ? *(const float4*)(b0 + 4096) : f4z();
            float4 qhm = hmok ? *(const float4*)(b0 + N3 - 64) : f4z();
            float4 qhp = hpok ? *(const float4*)(b0 + N3 + 64) : f4z();
            float4 c2  = *(const float4*)(b0 + 2 * N3);
            float4 wmq, wpq; WQ(c2, wmq, wpq);
            float4 Dsum = f4add(f4add(f4sub(qdp, qdm), f4sub(qhp, qhm)), f4sub(wpq, wmq));
            const float* tvs = &T[896 + u * 24];
            #pragma unroll
            for (int o = 0; o < 24; o++)
                acc[o] = f4fma(tvs[o], Dsum, acc[o]);
        }
    } else {
        // ---- scalar rows: D only -> T2sv ----
        float4 nc, ndm, ndp, nhm, nhp;
        LQ5(y + idx, nc, ndm, ndp, nhm, nhp);
        #pragma unroll 1
        for (int i = 0; i < 16; i++) {
            float4 c = nc, dmq = ndm, dpq = ndp, hmq = nhm, hpq = nhp;
            if (i < 15) LQ5(y + (i + 1) * N3 + idx, nc, ndm, ndp, nhm, nhp);
            float4 wmq, wpq; WQ(c, wmq, wpq);
            float4 Dd = f4sub(dpq, dmq), Dh = f4sub(hpq, hmq), Dw = f4sub(wpq, wmq);
            const float* tv = &T[768 + i * 8];
            #pragma unroll
            for (int jj = 0; jj < 8; jj++) {
                float wv = tv[jj];
                acc[jj * 3 + 0] = f4fma(wv, Dd, acc[jj * 3 + 0]);
                acc[jj * 3 + 1] = f4fma(wv, Dh, acc[jj * 3 + 1]);
                acc[jj * 3 + 2] = f4fma(wv, Dw, acc[jj * 3 + 2]);
            }
        }
        // ---- vector rows: vv0 + vv1, 3 explicit m-blocks per u ----
        #pragma unroll 1
        for (int u = 0; u < 8; u++) {
            const float* t0c = &T[1088 + u * 8];
            const float* t0f = &T[1152 + u * 8];
            const float* tv1 = &T[1216 + u * 8];
            {   // m=0: vv0 -> comp0; +k1*Dh -> comp2; -k1*Dw -> comp1
                float4 c, dmq, dpq, hmq, hpq;
                LQ5(y + (16 + u * 3 + 0) * N3 + idx, c, dmq, dpq, hmq, hpq);
                float4 wmq, wpq; WQ(c, wmq, wpq);
                float4 S = f4add(f4add(f4add(dmq, dpq), f4add(hmq, hpq)), f4add(wmq, wpq));
                float4 Dh = f4sub(hpq, hmq), Dw = f4sub(wpq, wmq);
                #pragma unroll
                for (int jj = 0; jj < 8; jj++) {
                    float k1 = tv1[jj];
                    acc[jj * 3 + 0] = f4fma(t0c[jj], c, f4fma(t0f[jj], S, acc[jj * 3 + 0]));
                    acc[jj * 3 + 2] = f4fma(k1, Dh, acc[jj * 3 + 2]);
                    acc[jj * 3 + 1] = f4fma(-k1, Dw, acc[jj * 3 + 1]);
                }
            }
            {   // m=1: vv0 -> comp1; +k1*Dw -> comp0; -k1*Dd -> comp2
                float4 c, dmq, dpq, hmq, hpq;
                LQ5(y + (16 + u * 3 + 1) * N3 + idx, c, dmq, dpq, hmq, hpq);
                float4 wmq, wpq; WQ(c, wmq, wpq);
                float4 S = f4add(f4add(f4add(dmq, dpq), f4add(hmq, hpq)), f4add(wmq, wpq));
                float4 Dd = f4sub(dpq, dmq), Dw = f4sub(wpq, wmq);
                #pragma unroll
                for (int jj = 0; jj < 8; jj++) {
                    float k1 = tv1[jj];
                    acc[jj * 3 + 1] = f4fma(t0c[jj], c, f4fma(t0f[jj], S, acc[jj * 3 + 1]));
                    acc[jj * 3 + 0] = f4fma(k1, Dw, acc[jj * 3 + 0]);
                    acc[jj * 3 + 2] = f4fma(-k1, Dd, acc[jj * 3 + 2]);
                }
            }
            {   // m=2: vv0 -> comp2; +k1*Dd -> comp1; -k1*Dh -> comp0
                float4 c, dmq, dpq, hmq, hpq;
                LQ5(y + (16 + u * 3 + 2) * N3 + idx, c, dmq, dpq, hmq, hpq);
                float4 wmq, wpq; WQ(c, wmq, wpq);
                float4 S = f4add(f4add(f4add(dmq, dpq), f4add(hmq, hpq)), f4add(wmq, wpq));
                float4 Dd = f4sub(dpq, dmq), Dh = f4sub(hpq, hmq);
                #pragma unroll
                for (int jj = 0; jj < 8; jj++) {
                    float k1 = tv1[jj];
                    acc[jj * 3 + 2] = f4fma(t0c[jj], c, f4fma(t0f[jj], S, acc[jj * 3 + 2]));
                    acc[jj * 3 + 1] = f4fma(k1, Dd, acc[jj * 3 + 1]);
                    acc[jj * 3 + 0] = f4fma(-k1, Dh, acc[jj * 3 + 0]);
                }
            }
        }
    }

    int obase = ohalf * 24;
    #pragma unroll
    for (int o = 0; o < 24; o++)
        *(float4*)(out + (obase + o) * N3 + idx) = acc[o];

    // fused BN partial stats
    int lane = threadIdx.x & 63, wvx = threadIdx.x >> 6;
    if (ohalf == 0) {
        #pragma unroll
        for (int q = 0; q < 48; q++) {
            float val = (q < 24) ? f4sum(acc[q]) : f4dot(acc[q - 24]);
            #pragma unroll
            for (int mq = 32; mq >= 1; mq >>= 1) val += __shfl_xor(val, mq, 64);
            if (lane == 0) red[wvx][q] = val;
        }
        __syncthreads();
        if (threadIdx.x < 48)
            atomicAdd(&stats[threadIdx.x],
                      red[0][threadIdx.x] + red[1][threadIdx.x] +
                      red[2][threadIdx.x] + red[3][threadIdx.x]);
    } else {
        #pragma unroll
        for (int q = 0; q < 24; q++) {
            float val = f4dot(acc[q]);
            #pragma unroll
            for (int mq = 32; mq >= 1; mq >>= 1) val += __shfl_xor(val, mq, 64);
            if (lane == 0) red[wvx][q] = val;
        }
        __syncthreads();
        if (threadIdx.x < 24)
            atomicAdd(&stats[48 + threadIdx.x],
                      red[0][threadIdx.x] + red[1][threadIdx.x] +
                      red[2][threadIdx.x] + red[3][threadIdx.x]);
    }
}

// ---------------------------------------------------------------------------
// BN apply + gate (finalize inlined): zp(48ch) -> out(40ch), float2/thread
// ---------------------------------------------------------------------------
__global__ __launch_bounds__(256) void bn_gate_kernel(const float* __restrict__ zp,
                                                      const float* __restrict__ stats,
                                                      const float* __restrict__ wsc,
                                                      const float* __restrict__ bsc,
                                                      const float* __restrict__ wvc,
                                                      float* __restrict__ out) {
    __shared__ float sb[56];
    if (threadIdx.x < 32) {
        int t = threadIdx.x;
        const float invN = 1.0f / 262144.0f;
        if (t < 24) {
            float mu = stats[t] * invN;
            float var = stats[24 + t] * invN - mu * mu;
            float inv = rsqrtf(var + 1e-5f);
            sb[t] = wsc[t] * inv;
            sb[24 + t] = bsc[t] - mu * wsc[t] * inv;
        } else {
            int u = t - 24;
            float s2 = stats[48 + u * 3] + stats[48 + u * 3 + 1] + stats[48 + u * 3 + 2];
            sb[48 + u] = wvc[u] * rsqrtf(s2 * invN + 1e-5f);
        }
    }
    __syncthreads();

    int idx = (blockIdx.x * 256 + threadIdx.x) * 2;
    float2 g[8];
    #pragma unroll
    for (int u = 0; u < 8; u++) {
        float2 v = *(const float2*)(zp + (16 + u) * N3 + idx);
        float sc = sb[16 + u], bi = sb[40 + u];
        g[u].x = 1.0f / (1.0f + expf(-(v.x * sc + bi)));
        g[u].y = 1.0f / (1.0f + expf(-(v.y * sc + bi)));
    }
    #pragma unroll
    for (int c = 0; c < 16; c++) {
        float2 v = *(const float2*)(zp + c * N3 + idx);
        float sc = sb[c], bi = sb[24 + c];
        float2 r;
        r.x = fmaxf(v.x * sc + bi, 0.f);
        r.y = fmaxf(v.y * sc + bi, 0.f);
        *(float2*)(out + c * N3 + idx) = r;
    }
    #pragma unroll
    for (int u = 0; u < 8; u++) {
        float sv = sb[48 + u];
        #pragma unroll
        for (int m = 0; m < 3; m++) {
            float2 v = *(const float2*)(zp + (24 + u * 3 + m) * N3 + idx);
            float2 r;
            r.x = v.x * sv * g[u].x;
            r.y = v.y * sv * g[u].y;
            *(float2*)(out + (16 + u * 3 + m) * N3 + idx) = r;
        }
    }
}

// ---------------------------------------------------------------------------
extern "C" void kernel_launch(void* const* d_in, const int* in_sizes, int n_in,
                              void* d_out, int out_size, void* d_ws, size_t ws_size,
                              hipStream_t stream) {
    const float* x      = (const float*)d_in[0];
    const float* w1     = (const float*)d_in[1];
    const float* sc1    = (const float*)d_in[2];
    const float* w2     = (const float*)d_in[3];
    const float* sc2s   = (const float*)d_in[4];
    const float* sc2v   = (const float*)d_in[5];
    const float* bn1_ws = (const float*)d_in[6];
    const float* bn1_bs = (const float*)d_in[7];
    const float* bn1_wv = (const float*)d_in[8];
    const float* bn2_ws = (const float*)d_in[9];
    const float* bn2_bs = (const float*)d_in[10];
    const float* bn2_wv = (const float*)d_in[11];
    float* out = (float*)d_out;
    char* ws = (char*)d_ws;

    float* Tg     = (float*)(ws + 0);        // 1728 floats
    float* stats1 = (float*)(ws + 8192);     // 72 floats
    float* stats2 = (float*)(ws + 8192 + 512);
    float* bufA   = (float*)(ws + 262144);   // 48*N3*4 = 50331648 B

    hipLaunchKernelGGL(build_tables_kernel, dim3(8), dim3(256), 0, stream,
                       w1, sc1, w2, sc2s, sc2v, Tg, stats1, stats2);
    hipLaunchKernelGGL(conv1_kernel, dim3(256, 2), dim3(256), 0, stream, x, Tg, bufA, stats1);
    hipLaunchKernelGGL(bn_gate_kernel, dim3(512), dim3(256), 0, stream,
                       bufA, stats1, bn1_ws, bn1_bs, bn1_wv, out);
    hipLaunchKernelGGL(conv2_kernel, dim3(256, 2), dim3(256), 0, stream, out, Tg, bufA, stats2);
    hipLaunchKernelGGL(bn_gate_kernel, dim3(512), dim3(256), 0, stream,
                       bufA, stats2, bn2_ws, bn2_bs, bn2_wv, out);
}